// Round 8
// baseline (638.891 us; speedup 1.0000x reference)
//
#include <hip/hip_runtime.h>
#include <cmath>

#pragma clang fp contract(off)

typedef unsigned long long ull;

#define NPRIORS 131072
#define NIMG 16
#define KSEL 5000
#define TOPK 750
#define SORTN 8192
#define MW 80                      // mask words per row (640 B, 16B-aligned)
#define NCHUNK 79
#define KSELP (NCHUNK * 64)        // 5056
#define NBIN 65536
#define NSLOT 16                   // sweep stage slots per region

// Exact midpoint between 0.3f and nextafterf(0.3f): fl32(inter/u) > 0.3f
// <=> (double)inter > MID03 * (double)uni  (25b x 24b product exact in double;
// tie at midpoint rounds to even mantissa = 0.3f, i.e. NOT >).
#define MID03 0.30000002682209014892578125

// ---------------- workspace layout ----------------
// ndiag aliases the pairs region: pairs are dead once rank_decode completes,
// before mask_build writes ndiag. (647 KB <= 1 MB.)
#define WS_PAIRS 0                                   // u64 [16][8192]   1 MB
#define WS_NDIAG 0                                   // u64 [16][KSELP] (aliased)
#define WS_MCNT 1048576                              // int [64]
#define WS_BOXES 1048832                             // f4  [16][5000]
#define WS_SCORES 2328832                            // f32 [16][5000]
#define WS_MASK 2649088                              // u64 [16][5000][80]  51.2 MB
#define WS_HIST (WS_MASK)                            // u32 [16][65536] (aliased, pre-mask)
#define WS_CNT  (WS_MASK + 4194304)                  // u32 [16][65536]
#define WS_POS  (WS_MASK + 8388608)                  // u32 [16][65536] (no memset needed)
#define WS_DIAG (WS_MASK + (size_t)NIMG * KSEL * MW * 8)   // 53,849,088

__device__ inline ull readlane64(ull t, int l) {
  unsigned lo = (unsigned)__builtin_amdgcn_readlane((int)(unsigned)t, l);
  unsigned hi = (unsigned)__builtin_amdgcn_readlane((int)(unsigned)(t >> 32), l);
  return ((ull)hi << 32) | lo;
}

// ============ Kernel 1: histogram on bin = (bits>>12)&0xFFFF ============
__global__ __launch_bounds__(256) void hist_kernel(const float* __restrict__ conf,
                                                   unsigned int* __restrict__ hist) {
  const int img = blockIdx.y;
  const float4* c4 = (const float4*)conf + (size_t)img * (NPRIORS / 2);
  unsigned int* H = hist + (size_t)img * NBIN;
  for (int q = blockIdx.x * 256 + threadIdx.x; q < NPRIORS / 2; q += 64 * 256) {
    float4 v = c4[q];
    if (v.y > 0.05f) atomicAdd(&H[(__float_as_uint(v.y) >> 12) & 0xFFFFu], 1u);
    if (v.w > 0.05f) atomicAdd(&H[(__float_as_uint(v.w) >> 12) & 0xFFFFu], 1u);
  }
}

// ============ Kernel 2: coalesced chunk-sum scan -> cutoff + bin bases ============
__global__ __launch_bounds__(1024) void cutoff_kernel(const unsigned int* __restrict__ hist,
                                                      unsigned int* __restrict__ pos,
                                                      int* __restrict__ meta,
                                                      float4* __restrict__ sboxes,
                                                      float* __restrict__ sscores) {
  const int img = blockIdx.x;
  const int tid = threadIdx.x;
  const int lane = tid & 63;
  const int wv = tid >> 6;
  const unsigned int* H = hist + (size_t)img * NBIN;
  unsigned int* P = pos + (size_t)img * NBIN;
  __shared__ unsigned int csum[1024];
  __shared__ unsigned int suf[1024];
  __shared__ int s_cc;
  __shared__ unsigned int s_cut, s_mc;

  // phase 1: chunk sums (chunk = 64 consecutive bins) via coalesced tiles
  for (int g = 0; g < 64; ++g) {
    unsigned int v = H[g * 1024 + tid];
    for (int m = 1; m < 64; m <<= 1) v += __shfl_xor(v, m);
    if (lane == 0) csum[g * 16 + wv] = v;
  }
  __syncthreads();
  // phase 2: inclusive suffix scan over 1024 chunks
  suf[tid] = csum[tid];
  if (tid == 0) s_cc = 0;
  __syncthreads();
  for (int off = 1; off < 1024; off <<= 1) {
    unsigned int v = (tid + off < 1024) ? suf[tid + off] : 0u;
    __syncthreads();
    suf[tid] += v;
    __syncthreads();
  }
  if (suf[tid] >= KSEL && (suf[tid] - csum[tid]) < KSEL) s_cc = tid;  // unique
  __syncthreads();
  const int cc = s_cc;
  if (tid == 0) { s_cut = (unsigned int)(cc * 64); s_mc = suf[0]; }  // degenerate default
  __syncthreads();
  // phase 3: per-bin exclusive-suffix bases for bins >= cc*64 only
  for (int b = cc * 64 + tid; b < NBIN; b += 1024) {
    int q = b >> 6;
    unsigned int acc = (q + 1 < 1024) ? suf[q + 1] : 0u;
    for (int b2 = b + 1; b2 < (q + 1) * 64; ++b2) acc += H[b2];
    P[b] = acc;
    unsigned int h = H[b];
    if (acc < KSEL && acc + h >= KSEL) { s_cut = (unsigned int)b; s_mc = acc + h; }  // unique
  }
  __syncthreads();
  if (tid == 0) {
    meta[img] = (int)min(s_mc, (unsigned int)SORTN);
    meta[16 + img] = (int)s_cut;
  }
  // default fill (overwritten by rank_decode for real slots)
  for (int i = tid; i < KSEL; i += 1024) {
    sboxes[(size_t)img * KSEL + i] = make_float4(0.f, 0.f, 0.f, 0.f);
    sscores[(size_t)img * KSEL + i] = -1e9f;
  }
}

// ============ Kernel 3: scatter candidates to bin-grouped slots ============
__global__ __launch_bounds__(256) void scatter_kernel(const float* __restrict__ conf,
                                                      const unsigned int* __restrict__ pos,
                                                      unsigned int* __restrict__ cnt,
                                                      const int* __restrict__ meta,
                                                      ull* __restrict__ pairs) {
  const int img = blockIdx.y;
  const float4* c4 = (const float4*)conf + (size_t)img * (NPRIORS / 2);
  const unsigned int* P = pos + (size_t)img * NBIN;
  unsigned int* Cn = cnt + (size_t)img * NBIN;
  ull* mypairs = pairs + (size_t)img * SORTN;
  const unsigned int cutval = ((unsigned int)meta[16 + img]) << 12;
  for (int q = blockIdx.x * 256 + threadIdx.x; q < NPRIORS / 2; q += 64 * 256) {
    float4 v = c4[q];
#pragma unroll
    for (int h = 0; h < 2; ++h) {
      float sc = h ? v.w : v.y;
      unsigned int p = 2 * (unsigned int)q + h;
      if (sc > 0.05f) {
        unsigned int u = __float_as_uint(sc);
        if (u >= cutval) {
          unsigned int bin = (u >> 12) & 0xFFFFu;
          unsigned int slot = atomicAdd(&Cn[bin], 1u);
          unsigned int idx = P[bin] + slot;
          if (idx < SORTN)
            mypairs[idx] = ((ull)u << 32) | (ull)(0xFFFFFFFFu - p);
        }
      }
    }
  }
}

// ============ Kernel 4: rank within bin (exact order) + SSD decode ============
__global__ __launch_bounds__(256) void rank_decode_kernel(const ull* __restrict__ pairs,
                                                          const unsigned int* __restrict__ hist,
                                                          const unsigned int* __restrict__ pos,
                                                          const int* __restrict__ meta,
                                                          const float* __restrict__ loc,
                                                          const float* __restrict__ prior,
                                                          float4* __restrict__ sboxes,
                                                          float* __restrict__ sscores) {
#pragma clang fp contract(off)
  const int img = blockIdx.y;
  const int s = blockIdx.x * 256 + threadIdx.x;
  const int mc = meta[img];
  if (s >= mc) return;
  const ull* mypairs = pairs + (size_t)img * SORTN;
  const ull key = mypairs[s];
  const unsigned int u = (unsigned int)(key >> 32);
  const unsigned int bin = (u >> 12) & 0xFFFFu;
  const unsigned int base = pos[(size_t)img * NBIN + bin];
  const unsigned int cb = hist[(size_t)img * NBIN + bin];
  const int end = min((int)(base + cb), mc);
  int rank = 0;
  for (int j = (int)base; j < end; ++j) rank += (mypairs[j] > key);
  const int fp = (int)base + rank;
  if (fp >= KSEL) return;
  const unsigned int p = 0xFFFFFFFFu - (unsigned int)(key & 0xFFFFFFFFu);
  const float* lp = loc + ((size_t)img * NPRIORS + p) * 4;
  const float* pp = prior + (size_t)p * 4;
  float l0 = lp[0], l1 = lp[1], l2 = lp[2], l3 = lp[3];
  float px = pp[0], py = pp[1], pw = pp[2], ph = pp[3];
  float cx = px + (l0 * 0.1f) * pw;
  float cy = py + (l1 * 0.1f) * ph;
  float w = pw * (float)exp((double)(l2 * 0.2f));
  float hh = ph * (float)exp((double)(l3 * 0.2f));
  float4 box;
  box.x = cx - w * 0.5f;
  box.y = cy - hh * 0.5f;
  box.z = cx + w * 0.5f;
  box.w = cy + hh * 0.5f;
  sboxes[(size_t)img * KSEL + fp] = box;
  sscores[(size_t)img * KSEL + fp] = __uint_as_float(u);
}

// ============ Kernel 5: IoU mask build — 128x256 tile per block + diag/ndiag ============
// diag[i]  = row i's word chunk(i)     (intra-chunk kills)
// ndiag[i] = row i's word chunk(i)+1   (next-chunk kills, for the lagged sweep)
__global__ __launch_bounds__(256) void mask_build_kernel(const float4* __restrict__ sboxes,
                                                         ull* __restrict__ mask,
                                                         ull* __restrict__ diag,
                                                         ull* __restrict__ ndiag) {
#pragma clang fp contract(off)
  const int jt = blockIdx.x;       // 0..19  (column tile of 256)
  const int sp = blockIdx.y;       // 0..39  (strip pair: strips 2sp, 2sp+1)
  const int img = blockIdx.z;
  if (jt < (sp >> 1)) return;      // fully below both strips
  const int tid = threadIdx.x;
  const int lane = tid & 63;
  const int wave = tid >> 6;
  __shared__ float4 ib[128];
  const float4* bb = sboxes + (size_t)img * KSEL;
  if (tid < 128) {
    int i = sp * 128 + tid;
    ib[tid] = (i < KSEL) ? bb[i] : make_float4(0.f, 0.f, 0.f, 0.f);
  }
  __syncthreads();
  float4 cb[4];
  float ca[4];
#pragma unroll
  for (int s = 0; s < 4; ++s) {
    int j = jt * 256 + s * 64 + lane;
    cb[s] = (j < KSEL) ? bb[j] : make_float4(0.f, 0.f, 0.f, 0.f);
    ca[s] = (cb[s].z - cb[s].x) * (cb[s].w - cb[s].y);
  }
  ull* mrow = mask + (size_t)img * KSEL * MW;
  ull* dg = diag + (size_t)img * KSELP;
  ull* ndg = ndiag + (size_t)img * KSELP;
  const int grp0 = jt * 4;
  for (int k = 0; k < 32; ++k) {
    const int rr = wave * 32 + k;           // 0..127 within strip pair
    const int strip = 2 * sp + (rr >> 6);
    const int r = rr & 63;
    const int i = sp * 128 + rr;
    const float4 pb = ib[rr];
    const float pa = (pb.z - pb.x) * (pb.w - pb.y);
    ull w[4];
#pragma unroll
    for (int s = 0; s < 4; ++s) {
      float ltx = fmaxf(pb.x, cb[s].x), lty = fmaxf(pb.y, cb[s].y);
      float rbx = fminf(pb.z, cb[s].z), rby = fminf(pb.w, cb[s].w);
      float ww = fmaxf(rbx - ltx, 0.0f), hh = fmaxf(rby - lty, 0.0f);
      float inter = ww * hh;
      float uni = fmaxf(pa + ca[s] - inter, 1e-12f);
      bool cond = ((grp0 + s) != strip) | (lane > r);
      bool kill = cond && ((double)inter > MID03 * (double)uni);
      w[s] = __ballot(kill);
    }
    if (lane == 0 && i < KSEL) {
      ull* wp = mrow + (size_t)i * MW + grp0;
      ((ulonglong2*)wp)[0] = make_ulonglong2(w[0], w[1]);
      ((ulonglong2*)wp)[1] = make_ulonglong2(w[2], w[3]);
#pragma unroll
      for (int s = 0; s < 4; ++s) {
        if (grp0 + s == strip) dg[i] = w[s];
        if (grp0 + s == strip + 1) ndg[i] = w[s];
      }
    }
  }
}

// ============ Kernel 6: serial greedy sweep — lagged flush, ndiag bridge ============
// remv invariant at chunk c: full rows of picks from chunks <= c-2 (flushed with
// vmcnt(NSLOT) one chunk late -> drain is free); chunk c-1 picks' word-c kills
// come from LDS ndiag gather + shfl-OR; intra-chunk kills from diag readlane.
__global__ __launch_bounds__(64) void sweep_kernel(const ull* __restrict__ mask,
                                                   const ull* __restrict__ diag,
                                                   const ull* __restrict__ ndiag,
                                                   const float4* __restrict__ sboxes,
                                                   const float* __restrict__ sscores,
                                                   const int* __restrict__ meta,
                                                   float* __restrict__ out) {
  const int img = blockIdx.x;
  const int lane = threadIdx.x;
  const int V = min(meta[img], KSEL);
  const ull* mb = mask + (size_t)img * KSEL * MW;
  const ull* dg = diag + (size_t)img * KSELP;
  const ull* ng = ndiag + (size_t)img * KSELP;
  __shared__ ull sdiag[KSELP];            // 40448 B
  __shared__ ull sndg[KSELP];             // 40448 B
  __shared__ ull stage[2 * NSLOT * 128];  // 32 KB: 2 regions x 16 slots x 1024 B
  __shared__ int picks[TOPK];
  __shared__ int s_n;
  const int lc = min(lane, 39);  // lane-owned mask words {2lc, 2lc+1}

  for (int o = lane * 2; o < KSELP; o += 128) {
    *(ulonglong2*)&sdiag[o] = *(const ulonglong2*)&dg[o];
    *(ulonglong2*)&sndg[o] = *(const ulonglong2*)&ng[o];
  }
  __syncthreads();

  ull rlo = 0ULL, rhi = 0ULL;  // remv words 2*lc, 2*lc+1
  int nkeep = 0;

  if (V > 0) {
    int reg = 0;                // current stage region
    int cstart = 0;             // nkeep at chunk start
    int pcount = 0, ppos = 0;   // prev chunk's picks
    bool pendingPrev = false;
    int lastrow = 0;
    ull dw = sdiag[lane];
    for (int c = 0; c * 64 < V; ++c) {
      const int base = c * 64;
      ull dwn = sdiag[min(base + 64 + lane, KSELP - 1)];
      ull t = (c & 1) ? rhi : rlo;
      ull cur = readlane64(t, c >> 1);
      // bridge: prev chunk picks' kills at word c via ndiag
      ull nd = 0ULL;
      if (lane < pcount) nd = sndg[picks[ppos + lane]];
      for (int m = 1; m < 64; m <<= 1) nd |= __shfl_xor(nd, m);
      cur |= nd;
      const int lim = V - base;
      ull validm = (lim >= 64) ? ~0ULL : ((~0ULL) >> (64 - lim));
      ull avail = (~cur) & validm;

      int nb = 0;
      bool full = false;
      while (avail != 0ULL) {
        int r = __builtin_ctzll(avail);
        int row = base + r;
        if (lane == 0) picks[nkeep] = row;
        lastrow = row;
        nkeep++;
        if (nkeep >= TOPK) { full = true; break; }
        __builtin_amdgcn_global_load_lds(
            (const __attribute__((address_space(1))) unsigned int*)(mb + (size_t)row * MW + 2 * lc),
            (__attribute__((address_space(3))) unsigned int*)&stage[(reg * NSLOT + nb) * 128], 16, 0, 0);
        nb++;
        ull dr = readlane64(dw, r);
        avail &= ~(dr | (1ULL << r));
        if (nb == NSLOT) {  // rare: >16 picks in one chunk
          if (pendingPrev) {
            __builtin_amdgcn_s_waitcnt(0x4F70);  // vmcnt(16)
            asm volatile("" ::: "memory");
#pragma unroll
            for (int q = 0; q < NSLOT; ++q) {
              ulonglong2 v = *(ulonglong2*)&stage[((1 - reg) * NSLOT + q) * 128 + 2 * lane];
              rlo |= v.x; rhi |= v.y;
            }
          }
          pendingPrev = true;
          reg = 1 - reg;
          nb = 0;
        }
      }
      if (full) break;
      // pad to exactly NSLOT fires (idempotent: lastrow was genuinely picked)
      for (; nb < NSLOT; ++nb)
        __builtin_amdgcn_global_load_lds(
            (const __attribute__((address_space(1))) unsigned int*)(mb + (size_t)lastrow * MW + 2 * lc),
            (__attribute__((address_space(3))) unsigned int*)&stage[(reg * NSLOT + nb) * 128], 16, 0, 0);
      // flush prev region (its DMAs are >= 1 chunk old -> near-zero wait)
      if (pendingPrev) {
        __builtin_amdgcn_s_waitcnt(0x4F70);  // vmcnt(16)
        asm volatile("" ::: "memory");
#pragma unroll
        for (int q = 0; q < NSLOT; ++q) {
          ulonglong2 v = *(ulonglong2*)&stage[((1 - reg) * NSLOT + q) * 128 + 2 * lane];
          rlo |= v.x; rhi |= v.y;
        }
      }
      pendingPrev = true;
      reg = 1 - reg;
      pcount = nkeep - cstart;
      ppos = cstart;
      cstart = nkeep;
      dw = dwn;
    }
  }
  __builtin_amdgcn_s_waitcnt(0xF70);  // vmcnt(0): drain before LDS teardown
  asm volatile("" ::: "memory");

  if (lane == 0) s_n = (nkeep < TOPK) ? nkeep : TOPK;
  __syncthreads();
  const int n = s_n;
  float* ob = out + (size_t)img * (2 * TOPK * 5) + TOPK * 5;  // class-1 slab
  for (int k = lane; k < n; k += 64) {
    int i = picks[k];
    float4 b = sboxes[(size_t)img * KSEL + i];
    float sc = sscores[(size_t)img * KSEL + i];
    float* o = ob + (size_t)k * 5;
    o[0] = sc; o[1] = b.x; o[2] = b.y; o[3] = b.z; o[4] = b.w;
  }
}

extern "C" void kernel_launch(void* const* d_in, const int* in_sizes, int n_in,
                              void* d_out, int out_size, void* d_ws, size_t ws_size,
                              hipStream_t stream) {
  const float* loc = (const float*)d_in[0];    // [16, 131072, 4]
  const float* conf = (const float*)d_in[1];   // [16*131072, 2]
  const float* prior = (const float*)d_in[2];  // [131072, 4]
  float* out = (float*)d_out;                  // [16, 2, 750, 5]

  char* ws = (char*)d_ws;
  ull* pairs = (ull*)(ws + WS_PAIRS);
  ull* ndiag = (ull*)(ws + WS_NDIAG);          // aliases pairs (dead after rank_decode)
  int* meta = (int*)(ws + WS_MCNT);
  float4* sboxes = (float4*)(ws + WS_BOXES);
  float* sscores = (float*)(ws + WS_SCORES);
  ull* mask = (ull*)(ws + WS_MASK);
  ull* diag = (ull*)(ws + WS_DIAG);
  unsigned int* hist = (unsigned int*)(ws + WS_HIST);
  unsigned int* cnt = (unsigned int*)(ws + WS_CNT);
  unsigned int* pos = (unsigned int*)(ws + WS_POS);

  hipMemsetAsync(d_out, 0, (size_t)out_size * sizeof(float), stream);
  hipMemsetAsync(ws + WS_HIST, 0, 2u * 4194304u, stream);  // hist+cnt (pos needs no init)

  {
    dim3 g(64, NIMG);
    hist_kernel<<<g, 256, 0, stream>>>(conf, hist);
  }
  cutoff_kernel<<<NIMG, 1024, 0, stream>>>(hist, pos, meta, sboxes, sscores);
  {
    dim3 g(64, NIMG);
    scatter_kernel<<<g, 256, 0, stream>>>(conf, pos, cnt, meta, pairs);
  }
  {
    dim3 g((SORTN + 255) / 256, NIMG);
    rank_decode_kernel<<<g, 256, 0, stream>>>(pairs, hist, pos, meta, loc, prior, sboxes, sscores);
  }
  {
    dim3 g(20, 40, NIMG);
    mask_build_kernel<<<g, 256, 0, stream>>>(sboxes, mask, diag, ndiag);
  }
  sweep_kernel<<<NIMG, 64, 0, stream>>>(mask, diag, ndiag, sboxes, sscores, meta, out);
}

// Round 10
// 586.314 us; speedup vs baseline: 1.0897x; 1.0897x over previous
//
#include <hip/hip_runtime.h>
#include <cmath>

#pragma clang fp contract(off)

typedef unsigned long long ull;

#define NPRIORS 131072
#define NIMG 16
#define KSEL 5000
#define TOPK 750
#define SORTN 8192
#define MW 80                      // mask words per row (640 B, 16B-aligned)
#define NCHUNK 79
#define KSELP (NCHUNK * 64)        // 5056
#define NBIN 65536
#define NSLOT 16                   // sweep stage slots per region

// Exact midpoint between 0.3f and nextafterf(0.3f): fl32(inter/u) > 0.3f
// <=> (double)inter > MID03 * (double)uni  (25b x 24b product exact in double;
// tie at midpoint rounds to even mantissa = 0.3f, i.e. NOT >).
#define MID03 0.30000002682209014892578125

// ---------------- workspace layout ----------------
// ndiag aliases the pairs region: pairs are dead once rank_decode completes,
// before mask_build writes ndiag. (647 KB <= 1 MB.)
#define WS_PAIRS 0                                   // u64 [16][8192]   1 MB
#define WS_NDIAG 0                                   // u64 [16][KSELP] (aliased)
#define WS_MCNT 1048576                              // int [64]
#define WS_BOXES 1048832                             // f4  [16][5000]
#define WS_SCORES 2328832                            // f32 [16][5000]
#define WS_MASK 2649088                              // u64 [16][5000][80]  51.2 MB
#define WS_HIST (WS_MASK)                            // u32 [16][65536] (aliased, pre-mask)
#define WS_CNT  (WS_MASK + 4194304)                  // u32 [16][65536]
#define WS_POS  (WS_MASK + 8388608)                  // u32 [16][65536] (no memset needed)
#define WS_DIAG (WS_MASK + (size_t)NIMG * KSEL * MW * 8)   // 53,849,088

__device__ inline ull readlane64(ull t, int l) {
  unsigned lo = (unsigned)__builtin_amdgcn_readlane((int)(unsigned)t, l);
  unsigned hi = (unsigned)__builtin_amdgcn_readlane((int)(unsigned)(t >> 32), l);
  return ((ull)hi << 32) | lo;
}

// ============ Kernel 1: histogram on bin = (bits>>12)&0xFFFF ============
__global__ __launch_bounds__(256) void hist_kernel(const float* __restrict__ conf,
                                                   unsigned int* __restrict__ hist) {
  const int img = blockIdx.y;
  const float4* c4 = (const float4*)conf + (size_t)img * (NPRIORS / 2);
  unsigned int* H = hist + (size_t)img * NBIN;
  for (int q = blockIdx.x * 256 + threadIdx.x; q < NPRIORS / 2; q += 64 * 256) {
    float4 v = c4[q];
    if (v.y > 0.05f) atomicAdd(&H[(__float_as_uint(v.y) >> 12) & 0xFFFFu], 1u);
    if (v.w > 0.05f) atomicAdd(&H[(__float_as_uint(v.w) >> 12) & 0xFFFFu], 1u);
  }
}

// ============ Kernel 2: coalesced chunk-sum scan -> cutoff + bin bases ============
__global__ __launch_bounds__(1024) void cutoff_kernel(const unsigned int* __restrict__ hist,
                                                      unsigned int* __restrict__ pos,
                                                      int* __restrict__ meta,
                                                      float4* __restrict__ sboxes,
                                                      float* __restrict__ sscores) {
  const int img = blockIdx.x;
  const int tid = threadIdx.x;
  const int lane = tid & 63;
  const int wv = tid >> 6;
  const unsigned int* H = hist + (size_t)img * NBIN;
  unsigned int* P = pos + (size_t)img * NBIN;
  __shared__ unsigned int csum[1024];
  __shared__ unsigned int suf[1024];
  __shared__ int s_cc;
  __shared__ unsigned int s_cut, s_mc;

  // phase 1: chunk sums (chunk = 64 consecutive bins) via coalesced tiles
  for (int g = 0; g < 64; ++g) {
    unsigned int v = H[g * 1024 + tid];
    for (int m = 1; m < 64; m <<= 1) v += __shfl_xor(v, m);
    if (lane == 0) csum[g * 16 + wv] = v;
  }
  __syncthreads();
  // phase 2: inclusive suffix scan over 1024 chunks
  suf[tid] = csum[tid];
  if (tid == 0) s_cc = 0;
  __syncthreads();
  for (int off = 1; off < 1024; off <<= 1) {
    unsigned int v = (tid + off < 1024) ? suf[tid + off] : 0u;
    __syncthreads();
    suf[tid] += v;
    __syncthreads();
  }
  if (suf[tid] >= KSEL && (suf[tid] - csum[tid]) < KSEL) s_cc = tid;  // unique
  __syncthreads();
  const int cc = s_cc;
  if (tid == 0) { s_cut = (unsigned int)(cc * 64); s_mc = suf[0]; }  // degenerate default
  __syncthreads();
  // phase 3: per-bin exclusive-suffix bases for bins >= cc*64 only
  for (int b = cc * 64 + tid; b < NBIN; b += 1024) {
    int q = b >> 6;
    unsigned int acc = (q + 1 < 1024) ? suf[q + 1] : 0u;
    for (int b2 = b + 1; b2 < (q + 1) * 64; ++b2) acc += H[b2];
    P[b] = acc;
    unsigned int h = H[b];
    if (acc < KSEL && acc + h >= KSEL) { s_cut = (unsigned int)b; s_mc = acc + h; }  // unique
  }
  __syncthreads();
  if (tid == 0) {
    meta[img] = (int)min(s_mc, (unsigned int)SORTN);
    meta[16 + img] = (int)s_cut;
  }
  // default fill (overwritten by rank_decode for real slots)
  for (int i = tid; i < KSEL; i += 1024) {
    sboxes[(size_t)img * KSEL + i] = make_float4(0.f, 0.f, 0.f, 0.f);
    sscores[(size_t)img * KSEL + i] = -1e9f;
  }
}

// ============ Kernel 3: scatter candidates to bin-grouped slots ============
__global__ __launch_bounds__(256) void scatter_kernel(const float* __restrict__ conf,
                                                      const unsigned int* __restrict__ pos,
                                                      unsigned int* __restrict__ cnt,
                                                      const int* __restrict__ meta,
                                                      ull* __restrict__ pairs) {
  const int img = blockIdx.y;
  const float4* c4 = (const float4*)conf + (size_t)img * (NPRIORS / 2);
  const unsigned int* P = pos + (size_t)img * NBIN;
  unsigned int* Cn = cnt + (size_t)img * NBIN;
  ull* mypairs = pairs + (size_t)img * SORTN;
  const unsigned int cutval = ((unsigned int)meta[16 + img]) << 12;
  for (int q = blockIdx.x * 256 + threadIdx.x; q < NPRIORS / 2; q += 64 * 256) {
    float4 v = c4[q];
#pragma unroll
    for (int h = 0; h < 2; ++h) {
      float sc = h ? v.w : v.y;
      unsigned int p = 2 * (unsigned int)q + h;
      if (sc > 0.05f) {
        unsigned int u = __float_as_uint(sc);
        if (u >= cutval) {
          unsigned int bin = (u >> 12) & 0xFFFFu;
          unsigned int slot = atomicAdd(&Cn[bin], 1u);
          unsigned int idx = P[bin] + slot;
          if (idx < SORTN)
            mypairs[idx] = ((ull)u << 32) | (ull)(0xFFFFFFFFu - p);
        }
      }
    }
  }
}

// ============ Kernel 4: rank within bin (exact order) + SSD decode ============
__global__ __launch_bounds__(256) void rank_decode_kernel(const ull* __restrict__ pairs,
                                                          const unsigned int* __restrict__ hist,
                                                          const unsigned int* __restrict__ pos,
                                                          const int* __restrict__ meta,
                                                          const float* __restrict__ loc,
                                                          const float* __restrict__ prior,
                                                          float4* __restrict__ sboxes,
                                                          float* __restrict__ sscores) {
#pragma clang fp contract(off)
  const int img = blockIdx.y;
  const int s = blockIdx.x * 256 + threadIdx.x;
  const int mc = meta[img];
  if (s >= mc) return;
  const ull* mypairs = pairs + (size_t)img * SORTN;
  const ull key = mypairs[s];
  const unsigned int u = (unsigned int)(key >> 32);
  const unsigned int bin = (u >> 12) & 0xFFFFu;
  const unsigned int base = pos[(size_t)img * NBIN + bin];
  const unsigned int cb = hist[(size_t)img * NBIN + bin];
  const int end = min((int)(base + cb), mc);
  int rank = 0;
  for (int j = (int)base; j < end; ++j) rank += (mypairs[j] > key);
  const int fp = (int)base + rank;
  if (fp >= KSEL) return;
  const unsigned int p = 0xFFFFFFFFu - (unsigned int)(key & 0xFFFFFFFFu);
  const float* lp = loc + ((size_t)img * NPRIORS + p) * 4;
  const float* pp = prior + (size_t)p * 4;
  float l0 = lp[0], l1 = lp[1], l2 = lp[2], l3 = lp[3];
  float px = pp[0], py = pp[1], pw = pp[2], ph = pp[3];
  float cx = px + (l0 * 0.1f) * pw;
  float cy = py + (l1 * 0.1f) * ph;
  float w = pw * (float)exp((double)(l2 * 0.2f));
  float hh = ph * (float)exp((double)(l3 * 0.2f));
  float4 box;
  box.x = cx - w * 0.5f;
  box.y = cy - hh * 0.5f;
  box.z = cx + w * 0.5f;
  box.w = cy + hh * 0.5f;
  sboxes[(size_t)img * KSEL + fp] = box;
  sscores[(size_t)img * KSEL + fp] = __uint_as_float(u);
}

// ============ Kernel 5: IoU mask build — 128x256 tile per block + diag/ndiag ============
// diag[i]  = row i's word chunk(i)     (intra-chunk kills)
// ndiag[i] = row i's word chunk(i)+1   (next-chunk kills, for the lagged sweep)
__global__ __launch_bounds__(256) void mask_build_kernel(const float4* __restrict__ sboxes,
                                                         ull* __restrict__ mask,
                                                         ull* __restrict__ diag,
                                                         ull* __restrict__ ndiag) {
#pragma clang fp contract(off)
  const int jt = blockIdx.x;       // 0..19  (column tile of 256)
  const int sp = blockIdx.y;       // 0..39  (strip pair: strips 2sp, 2sp+1)
  const int img = blockIdx.z;
  if (jt < (sp >> 1)) return;      // fully below both strips
  const int tid = threadIdx.x;
  const int lane = tid & 63;
  const int wave = tid >> 6;
  __shared__ float4 ib[128];
  const float4* bb = sboxes + (size_t)img * KSEL;
  if (tid < 128) {
    int i = sp * 128 + tid;
    ib[tid] = (i < KSEL) ? bb[i] : make_float4(0.f, 0.f, 0.f, 0.f);
  }
  __syncthreads();
  float4 cb[4];
  float ca[4];
#pragma unroll
  for (int s = 0; s < 4; ++s) {
    int j = jt * 256 + s * 64 + lane;
    cb[s] = (j < KSEL) ? bb[j] : make_float4(0.f, 0.f, 0.f, 0.f);
    ca[s] = (cb[s].z - cb[s].x) * (cb[s].w - cb[s].y);
  }
  ull* mrow = mask + (size_t)img * KSEL * MW;
  ull* dg = diag + (size_t)img * KSELP;
  ull* ndg = ndiag + (size_t)img * KSELP;
  const int grp0 = jt * 4;
  for (int k = 0; k < 32; ++k) {
    const int rr = wave * 32 + k;           // 0..127 within strip pair
    const int strip = 2 * sp + (rr >> 6);
    const int r = rr & 63;
    const int i = sp * 128 + rr;
    const float4 pb = ib[rr];
    const float pa = (pb.z - pb.x) * (pb.w - pb.y);
    ull w[4];
#pragma unroll
    for (int s = 0; s < 4; ++s) {
      float ltx = fmaxf(pb.x, cb[s].x), lty = fmaxf(pb.y, cb[s].y);
      float rbx = fminf(pb.z, cb[s].z), rby = fminf(pb.w, cb[s].w);
      float ww = fmaxf(rbx - ltx, 0.0f), hh = fmaxf(rby - lty, 0.0f);
      float inter = ww * hh;
      float uni = fmaxf(pa + ca[s] - inter, 1e-12f);
      bool cond = ((grp0 + s) != strip) | (lane > r);
      bool kill = cond && ((double)inter > MID03 * (double)uni);
      w[s] = __ballot(kill);
    }
    if (lane == 0 && i < KSEL) {
      ull* wp = mrow + (size_t)i * MW + grp0;
      ((ulonglong2*)wp)[0] = make_ulonglong2(w[0], w[1]);
      ((ulonglong2*)wp)[1] = make_ulonglong2(w[2], w[3]);
#pragma unroll
      for (int s = 0; s < 4; ++s) {
        if (grp0 + s == strip) dg[i] = w[s];
        if (grp0 + s == strip + 1) ndg[i] = w[s];
      }
    }
  }
}

// ============ Kernel 6: serial greedy sweep — lagged flush, readlane bridge ============
// remv invariant at chunk c: full rows of picks from chunks <= c-2 (flushed one
// chunk late via pad-to-16 + vmcnt(16) -> drain is free); chunk c-1 picks' word-c
// kills accumulated during c-1's walk via readlane64(ndw, r) (bridge, off the
// critical chain); intra-chunk kills via readlane64(dw, r). dw/ndw are per-lane
// registers loaded from global with one-chunk prefetch (no LDS preload).
__global__ __launch_bounds__(64) void sweep_kernel(const ull* __restrict__ mask,
                                                   const ull* __restrict__ diag,
                                                   const ull* __restrict__ ndiag,
                                                   const float4* __restrict__ sboxes,
                                                   const float* __restrict__ sscores,
                                                   const int* __restrict__ meta,
                                                   float* __restrict__ out) {
  const int img = blockIdx.x;
  const int lane = threadIdx.x;
  const int V = min(meta[img], KSEL);
  const ull* mb = mask + (size_t)img * KSEL * MW;
  const ull* dg = diag + (size_t)img * KSELP;
  const ull* ng = ndiag + (size_t)img * KSELP;
  __shared__ ull stage[2 * NSLOT * 128];  // 32 KB: 2 regions x 16 slots x 1024 B
  __shared__ int picks[TOPK];
  __shared__ int s_n;
  const int lc = min(lane, 39);  // lane-owned mask words {2lc, 2lc+1}

  ull rlo = 0ULL, rhi = 0ULL;  // remv words 2*lc, 2*lc+1
  int nkeep = 0;

  if (V > 0) {
    int reg = 0;
    bool pendingPrev = false;
    int lastrow = 0;
    ull bridge = 0ULL;           // uniform across lanes (built via readlane)
    ull dw = dg[lane];           // chunk 0: diag / next-diag words
    ull ndw = ng[lane];
    for (int c = 0; c * 64 < V; ++c) {
      const int base = c * 64;
      // prefetch next chunk's diag words from global (off critical path)
      const int nidx = min(base + 64 + lane, KSELP - 1);
      ull dwn = dg[nidx];
      ull ndwn = ng[nidx];
      ull t = (c & 1) ? rhi : rlo;
      ull cur = readlane64(t, c >> 1) | bridge;
      bridge = 0ULL;
      const int lim = V - base;
      ull validm = (lim >= 64) ? ~0ULL : ((~0ULL) >> (64 - lim));
      ull avail = (~cur) & validm;

      int nb = 0;
      bool full = false;
      while (avail != 0ULL) {
        int r = __builtin_ctzll(avail);
        int row = base + r;
        if (lane == 0) picks[nkeep] = row;
        lastrow = row;
        nkeep++;
        if (nkeep >= TOPK) { full = true; break; }
        __builtin_amdgcn_global_load_lds(
            (const __attribute__((address_space(1))) unsigned int*)(mb + (size_t)row * MW + 2 * lc),
            (__attribute__((address_space(3))) unsigned int*)&stage[(reg * NSLOT + nb) * 128], 16, 0, 0);
        nb++;
        ull dr = readlane64(dw, r);           // critical chain
        bridge |= readlane64(ndw, r);         // off-chain bridge accumulate
        avail &= ~(dr | (1ULL << r));
        if (nb == NSLOT) {  // rare: >16 picks in one chunk
          if (pendingPrev) {
            __builtin_amdgcn_s_waitcnt(0x4F70);  // vmcnt(16): drain prev region only
            asm volatile("" ::: "memory");
#pragma unroll
            for (int q = 0; q < NSLOT; ++q) {
              ulonglong2 v = *(ulonglong2*)&stage[((1 - reg) * NSLOT + q) * 128 + 2 * lane];
              rlo |= v.x; rhi |= v.y;
            }
          }
          pendingPrev = true;
          reg = 1 - reg;
          nb = 0;
        }
      }
      if (full) break;
      // pad to exactly NSLOT fires (idempotent re-fires of a genuinely picked row)
      for (; nb < NSLOT; ++nb)
        __builtin_amdgcn_global_load_lds(
            (const __attribute__((address_space(1))) unsigned int*)(mb + (size_t)lastrow * MW + 2 * lc),
            (__attribute__((address_space(3))) unsigned int*)&stage[(reg * NSLOT + nb) * 128], 16, 0, 0);
      // flush prev region: its 16 DMAs are >= 1 chunk old -> near-zero wait
      if (pendingPrev) {
        __builtin_amdgcn_s_waitcnt(0x4F70);  // vmcnt(16)
        asm volatile("" ::: "memory");
#pragma unroll
        for (int q = 0; q < NSLOT; ++q) {
          ulonglong2 v = *(ulonglong2*)&stage[((1 - reg) * NSLOT + q) * 128 + 2 * lane];
          rlo |= v.x; rhi |= v.y;
        }
      }
      pendingPrev = true;
      reg = 1 - reg;
      dw = dwn;
      ndw = ndwn;
    }
  }
  __builtin_amdgcn_s_waitcnt(0xF70);  // vmcnt(0): drain before LDS teardown
  asm volatile("" ::: "memory");

  if (lane == 0) s_n = (nkeep < TOPK) ? nkeep : TOPK;
  __syncthreads();
  const int n = s_n;
  float* ob = out + (size_t)img * (2 * TOPK * 5) + TOPK * 5;  // class-1 slab
  for (int k = lane; k < n; k += 64) {
    int i = picks[k];
    float4 b = sboxes[(size_t)img * KSEL + i];
    float sc = sscores[(size_t)img * KSEL + i];
    float* o = ob + (size_t)k * 5;
    o[0] = sc; o[1] = b.x; o[2] = b.y; o[3] = b.z; o[4] = b.w;
  }
}

extern "C" void kernel_launch(void* const* d_in, const int* in_sizes, int n_in,
                              void* d_out, int out_size, void* d_ws, size_t ws_size,
                              hipStream_t stream) {
  const float* loc = (const float*)d_in[0];    // [16, 131072, 4]
  const float* conf = (const float*)d_in[1];   // [16*131072, 2]
  const float* prior = (const float*)d_in[2];  // [131072, 4]
  float* out = (float*)d_out;                  // [16, 2, 750, 5]

  char* ws = (char*)d_ws;
  ull* pairs = (ull*)(ws + WS_PAIRS);
  ull* ndiag = (ull*)(ws + WS_NDIAG);          // aliases pairs (dead after rank_decode)
  int* meta = (int*)(ws + WS_MCNT);
  float4* sboxes = (float4*)(ws + WS_BOXES);
  float* sscores = (float*)(ws + WS_SCORES);
  ull* mask = (ull*)(ws + WS_MASK);
  ull* diag = (ull*)(ws + WS_DIAG);
  unsigned int* hist = (unsigned int*)(ws + WS_HIST);
  unsigned int* cnt = (unsigned int*)(ws + WS_CNT);
  unsigned int* pos = (unsigned int*)(ws + WS_POS);

  hipMemsetAsync(d_out, 0, (size_t)out_size * sizeof(float), stream);
  hipMemsetAsync(ws + WS_HIST, 0, 2u * 4194304u, stream);  // hist+cnt (pos needs no init)

  {
    dim3 g(64, NIMG);
    hist_kernel<<<g, 256, 0, stream>>>(conf, hist);
  }
  cutoff_kernel<<<NIMG, 1024, 0, stream>>>(hist, pos, meta, sboxes, sscores);
  {
    dim3 g(64, NIMG);
    scatter_kernel<<<g, 256, 0, stream>>>(conf, pos, cnt, meta, pairs);
  }
  {
    dim3 g((SORTN + 255) / 256, NIMG);
    rank_decode_kernel<<<g, 256, 0, stream>>>(pairs, hist, pos, meta, loc, prior, sboxes, sscores);
  }
  {
    dim3 g(20, 40, NIMG);
    mask_build_kernel<<<g, 256, 0, stream>>>(sboxes, mask, diag, ndiag);
  }
  sweep_kernel<<<NIMG, 64, 0, stream>>>(mask, diag, ndiag, sboxes, sscores, meta, out);
}

// Round 13
// 534.389 us; speedup vs baseline: 1.1956x; 1.0972x over previous
//
#include <hip/hip_runtime.h>
#include <cmath>

#pragma clang fp contract(off)

typedef unsigned long long ull;

#define NPRIORS 131072
#define NIMG 16
#define KSEL 5000
#define TOPK 750
#define SORTN 8192
#define MW 80                      // mask words per row (640 B, 16B-aligned)
#define NCHUNK 79
#define KSELP (NCHUNK * 64)        // 5056
#define NBIN 65536

// Exact midpoint between 0.3f and nextafterf(0.3f): fl32(inter/u) > 0.3f
// <=> (double)inter > MID03 * (double)uni  (25b x 24b product exact in double;
// tie at midpoint rounds to even mantissa = 0.3f, i.e. NOT >).
#define MID03 0.30000002682209014892578125

// ---------------- workspace layout ----------------
// ndiag aliases the pairs region: pairs are dead once rank_decode completes,
// before mask_build writes ndiag. (647 KB <= 1 MB.)
#define WS_PAIRS 0                                   // u64 [16][8192]   1 MB
#define WS_NDIAG 0                                   // u64 [16][KSELP] (aliased)
#define WS_MCNT 1048576                              // int [64]
#define WS_BOXES 1048832                             // f4  [16][5000]
#define WS_SCORES 2328832                            // f32 [16][5000]
#define WS_MASK 2649088                              // u64 [16][5000][80]  51.2 MB
#define WS_HIST (WS_MASK)                            // u32 [16][65536] (aliased, pre-mask)
#define WS_CNT  (WS_MASK + 4194304)                  // u32 [16][65536]
#define WS_POS  (WS_MASK + 8388608)                  // u32 [16][65536] (no memset needed)
#define WS_DIAG (WS_MASK + (size_t)NIMG * KSEL * MW * 8)   // 53,849,088

__device__ inline ull readlane64(ull t, int l) {
  unsigned lo = (unsigned)__builtin_amdgcn_readlane((int)(unsigned)t, l);
  unsigned hi = (unsigned)__builtin_amdgcn_readlane((int)(unsigned)(t >> 32), l);
  return ((ull)hi << 32) | lo;
}

// workgroup barrier WITHOUT the vmcnt(0) drain __syncthreads carries:
// LDS traffic is ordered (lgkmcnt), in-flight global loads stay in flight.
__device__ inline void softBarrier() {
  asm volatile("s_waitcnt lgkmcnt(0)\n\ts_barrier" ::: "memory");
}

// ============ Kernel 1: histogram on bin = (bits>>12)&0xFFFF ============
__global__ __launch_bounds__(256) void hist_kernel(const float* __restrict__ conf,
                                                   unsigned int* __restrict__ hist) {
  const int img = blockIdx.y;
  const float4* c4 = (const float4*)conf + (size_t)img * (NPRIORS / 2);
  unsigned int* H = hist + (size_t)img * NBIN;
  for (int q = blockIdx.x * 256 + threadIdx.x; q < NPRIORS / 2; q += 64 * 256) {
    float4 v = c4[q];
    if (v.y > 0.05f) atomicAdd(&H[(__float_as_uint(v.y) >> 12) & 0xFFFFu], 1u);
    if (v.w > 0.05f) atomicAdd(&H[(__float_as_uint(v.w) >> 12) & 0xFFFFu], 1u);
  }
}

// ============ Kernel 2: coalesced chunk-sum scan -> cutoff + bin bases ============
__global__ __launch_bounds__(1024) void cutoff_kernel(const unsigned int* __restrict__ hist,
                                                      unsigned int* __restrict__ pos,
                                                      int* __restrict__ meta,
                                                      float4* __restrict__ sboxes,
                                                      float* __restrict__ sscores) {
  const int img = blockIdx.x;
  const int tid = threadIdx.x;
  const int lane = tid & 63;
  const int wv = tid >> 6;
  const unsigned int* H = hist + (size_t)img * NBIN;
  unsigned int* P = pos + (size_t)img * NBIN;
  __shared__ unsigned int csum[1024];
  __shared__ unsigned int suf[1024];
  __shared__ int s_cc;
  __shared__ unsigned int s_cut, s_mc;

  // phase 1: chunk sums (chunk = 64 consecutive bins) via coalesced tiles
  for (int g = 0; g < 64; ++g) {
    unsigned int v = H[g * 1024 + tid];
    for (int m = 1; m < 64; m <<= 1) v += __shfl_xor(v, m);
    if (lane == 0) csum[g * 16 + wv] = v;
  }
  __syncthreads();
  // phase 2: inclusive suffix scan over 1024 chunks
  suf[tid] = csum[tid];
  if (tid == 0) s_cc = 0;
  __syncthreads();
  for (int off = 1; off < 1024; off <<= 1) {
    unsigned int v = (tid + off < 1024) ? suf[tid + off] : 0u;
    __syncthreads();
    suf[tid] += v;
    __syncthreads();
  }
  if (suf[tid] >= KSEL && (suf[tid] - csum[tid]) < KSEL) s_cc = tid;  // unique
  __syncthreads();
  const int cc = s_cc;
  if (tid == 0) { s_cut = (unsigned int)(cc * 64); s_mc = suf[0]; }  // degenerate default
  __syncthreads();
  // phase 3: per-bin exclusive-suffix bases for bins >= cc*64 only
  for (int b = cc * 64 + tid; b < NBIN; b += 1024) {
    int q = b >> 6;
    unsigned int acc = (q + 1 < 1024) ? suf[q + 1] : 0u;
    for (int b2 = b + 1; b2 < (q + 1) * 64; ++b2) acc += H[b2];
    P[b] = acc;
    unsigned int h = H[b];
    if (acc < KSEL && acc + h >= KSEL) { s_cut = (unsigned int)b; s_mc = acc + h; }  // unique
  }
  __syncthreads();
  if (tid == 0) {
    meta[img] = (int)min(s_mc, (unsigned int)SORTN);
    meta[16 + img] = (int)s_cut;
  }
  // default fill (overwritten by rank_decode for real slots)
  for (int i = tid; i < KSEL; i += 1024) {
    sboxes[(size_t)img * KSEL + i] = make_float4(0.f, 0.f, 0.f, 0.f);
    sscores[(size_t)img * KSEL + i] = -1e9f;
  }
}

// ============ Kernel 3: scatter candidates to bin-grouped slots ============
__global__ __launch_bounds__(256) void scatter_kernel(const float* __restrict__ conf,
                                                      const unsigned int* __restrict__ pos,
                                                      unsigned int* __restrict__ cnt,
                                                      const int* __restrict__ meta,
                                                      ull* __restrict__ pairs) {
  const int img = blockIdx.y;
  const float4* c4 = (const float4*)conf + (size_t)img * (NPRIORS / 2);
  const unsigned int* P = pos + (size_t)img * NBIN;
  unsigned int* Cn = cnt + (size_t)img * NBIN;
  ull* mypairs = pairs + (size_t)img * SORTN;
  const unsigned int cutval = ((unsigned int)meta[16 + img]) << 12;
  for (int q = blockIdx.x * 256 + threadIdx.x; q < NPRIORS / 2; q += 64 * 256) {
    float4 v = c4[q];
#pragma unroll
    for (int h = 0; h < 2; ++h) {
      float sc = h ? v.w : v.y;
      unsigned int p = 2 * (unsigned int)q + h;
      if (sc > 0.05f) {
        unsigned int u = __float_as_uint(sc);
        if (u >= cutval) {
          unsigned int bin = (u >> 12) & 0xFFFFu;
          unsigned int slot = atomicAdd(&Cn[bin], 1u);
          unsigned int idx = P[bin] + slot;
          if (idx < SORTN)
            mypairs[idx] = ((ull)u << 32) | (ull)(0xFFFFFFFFu - p);
        }
      }
    }
  }
}

// ============ Kernel 4: rank within bin (exact order) + SSD decode ============
__global__ __launch_bounds__(256) void rank_decode_kernel(const ull* __restrict__ pairs,
                                                          const unsigned int* __restrict__ hist,
                                                          const unsigned int* __restrict__ pos,
                                                          const int* __restrict__ meta,
                                                          const float* __restrict__ loc,
                                                          const float* __restrict__ prior,
                                                          float4* __restrict__ sboxes,
                                                          float* __restrict__ sscores) {
#pragma clang fp contract(off)
  const int img = blockIdx.y;
  const int s = blockIdx.x * 256 + threadIdx.x;
  const int mc = meta[img];
  if (s >= mc) return;
  const ull* mypairs = pairs + (size_t)img * SORTN;
  const ull key = mypairs[s];
  const unsigned int u = (unsigned int)(key >> 32);
  const unsigned int bin = (u >> 12) & 0xFFFFu;
  const unsigned int base = pos[(size_t)img * NBIN + bin];
  const unsigned int cb = hist[(size_t)img * NBIN + bin];
  const int end = min((int)(base + cb), mc);
  int rank = 0;
  for (int j = (int)base; j < end; ++j) rank += (mypairs[j] > key);
  const int fp = (int)base + rank;
  if (fp >= KSEL) return;
  const unsigned int p = 0xFFFFFFFFu - (unsigned int)(key & 0xFFFFFFFFu);
  const float* lp = loc + ((size_t)img * NPRIORS + p) * 4;
  const float* pp = prior + (size_t)p * 4;
  float l0 = lp[0], l1 = lp[1], l2 = lp[2], l3 = lp[3];
  float px = pp[0], py = pp[1], pw = pp[2], ph = pp[3];
  float cx = px + (l0 * 0.1f) * pw;
  float cy = py + (l1 * 0.1f) * ph;
  float w = pw * (float)exp((double)(l2 * 0.2f));
  float hh = ph * (float)exp((double)(l3 * 0.2f));
  float4 box;
  box.x = cx - w * 0.5f;
  box.y = cy - hh * 0.5f;
  box.z = cx + w * 0.5f;
  box.w = cy + hh * 0.5f;
  sboxes[(size_t)img * KSEL + fp] = box;
  sscores[(size_t)img * KSEL + fp] = __uint_as_float(u);
}

// ============ Kernel 5: IoU mask build — 128x256 tile per block + diag/ndiag ============
// diag[i]  = row i's word chunk(i)     (intra-chunk kills)
// ndiag[i] = row i's word chunk(i)+1   (next-chunk kills, for the lagged sweep)
__global__ __launch_bounds__(256) void mask_build_kernel(const float4* __restrict__ sboxes,
                                                         ull* __restrict__ mask,
                                                         ull* __restrict__ diag,
                                                         ull* __restrict__ ndiag) {
#pragma clang fp contract(off)
  const int jt = blockIdx.x;       // 0..19  (column tile of 256)
  const int sp = blockIdx.y;       // 0..39  (strip pair: strips 2sp, 2sp+1)
  const int img = blockIdx.z;
  if (jt < (sp >> 1)) return;      // fully below both strips
  const int tid = threadIdx.x;
  const int lane = tid & 63;
  const int wave = tid >> 6;
  __shared__ float4 ib[128];
  const float4* bb = sboxes + (size_t)img * KSEL;
  if (tid < 128) {
    int i = sp * 128 + tid;
    ib[tid] = (i < KSEL) ? bb[i] : make_float4(0.f, 0.f, 0.f, 0.f);
  }
  __syncthreads();
  float4 cb[4];
  float ca[4];
#pragma unroll
  for (int s = 0; s < 4; ++s) {
    int j = jt * 256 + s * 64 + lane;
    cb[s] = (j < KSEL) ? bb[j] : make_float4(0.f, 0.f, 0.f, 0.f);
    ca[s] = (cb[s].z - cb[s].x) * (cb[s].w - cb[s].y);
  }
  ull* mrow = mask + (size_t)img * KSEL * MW;
  ull* dg = diag + (size_t)img * KSELP;
  ull* ndg = ndiag + (size_t)img * KSELP;
  const int grp0 = jt * 4;
  for (int k = 0; k < 32; ++k) {
    const int rr = wave * 32 + k;           // 0..127 within strip pair
    const int strip = 2 * sp + (rr >> 6);
    const int r = rr & 63;
    const int i = sp * 128 + rr;
    const float4 pb = ib[rr];
    const float pa = (pb.z - pb.x) * (pb.w - pb.y);
    ull w[4];
#pragma unroll
    for (int s = 0; s < 4; ++s) {
      float ltx = fmaxf(pb.x, cb[s].x), lty = fmaxf(pb.y, cb[s].y);
      float rbx = fminf(pb.z, cb[s].z), rby = fminf(pb.w, cb[s].w);
      float ww = fmaxf(rbx - ltx, 0.0f), hh = fmaxf(rby - lty, 0.0f);
      float inter = ww * hh;
      float uni = fmaxf(pa + ca[s] - inter, 1e-12f);
      bool cond = ((grp0 + s) != strip) | (lane > r);
      bool kill = cond && ((double)inter > MID03 * (double)uni);
      w[s] = __ballot(kill);
    }
    if (lane == 0 && i < KSEL) {
      ull* wp = mrow + (size_t)i * MW + grp0;
      ((ulonglong2*)wp)[0] = make_ulonglong2(w[0], w[1]);
      ((ulonglong2*)wp)[1] = make_ulonglong2(w[2], w[3]);
#pragma unroll
      for (int s = 0; s < 4; ++s) {
        if (grp0 + s == strip) dg[i] = w[s];
        if (grp0 + s == strip + 1) ndg[i] = w[s];
      }
    }
  }
}

// ============ Kernel 6: sweep — producer/consumer wave pair ============
// Wave A (tid<64): scalar walker. Per chunk k: cur = mailbox[k] | bridge;
//   ctz-walk with readlane64(dw,r); bridge |= readlane64(ndw,r); picks -> LDS.
//   Only VMEM: diag/ndiag prefetch one chunk ahead (own vmcnt, zero stall).
// Wave B: servicer. Per chunk k: OR full rows of chunk k-1's picks into its
//   register-distributed remv (16 clamped unconditional dwordx4 -> ONE latency,
//   B's own vmcnt wait, off A's path); publish remv word k+1 to mailbox.
// Invariant at A's chunk k: mailbox[k] = kills from picks of chunks <= k-2
//   (mailbox[0] and mailbox[1] are 0 by definition - BOTH must be zero-inited:
//   B's first publish is mailbox[2] at its k=1 step. R11 bug: mailbox[1] was
//   read uninitialized); bridge = chunk k-1 picks' word-k kills (via ndiag).
// Identical decisions to the single-wave R10 sweep. Per-chunk raw barrier
// WITHOUT vmcnt drain.
__global__ __launch_bounds__(128) void sweep_kernel(const ull* __restrict__ mask,
                                                    const ull* __restrict__ diag,
                                                    const ull* __restrict__ ndiag,
                                                    const float4* __restrict__ sboxes,
                                                    const float* __restrict__ sscores,
                                                    const int* __restrict__ meta,
                                                    float* __restrict__ out) {
  const int img = blockIdx.x;
  const int tid = threadIdx.x;
  const int lane = tid & 63;
  const bool waveA = (tid < 64);
  const int V = min(meta[img], KSEL);
  const ull* mb = mask + (size_t)img * KSEL * MW;
  const ull* dg = diag + (size_t)img * KSELP;
  const ull* ng = ndiag + (size_t)img * KSELP;
  __shared__ ull mailbox[NCHUNK + 1];
  __shared__ int pickbuf[TOPK];
  __shared__ int s_np[NCHUNK];
  __shared__ int s_start[NCHUNK];
  __shared__ int s_done;
  __shared__ int s_n;
  const int lc = min(lane, 39);  // B: lane-owned remv words {2lc, 2lc+1}

  // zero the WHOLE mailbox: mailbox[0] and mailbox[1] are consumed before
  // wave B's first publish (which is mailbox[2]).
  for (int i = tid; i <= NCHUNK; i += 128) mailbox[i] = 0ULL;
  if (tid == 0) { s_done = 0; s_n = 0; }
  __syncthreads();

  if (V > 0) {
    // wave-private state
    ull dw = 0, ndw = 0, bridge = 0;       // A
    ull rlo = 0, rhi = 0;                  // B
    int nkeep = 0;
    bool adone = false;
    if (waveA) { dw = dg[lane]; ndw = ng[lane]; }

    for (int k = 0; k < NCHUNK; ++k) {
      softBarrier();
      if (s_done) break;  // uniform LDS value: both waves break together
      if (waveA) {
        if (!adone) {
          const int base = k * 64;
          // prefetch next chunk's diag words (used next step; own vmcnt)
          const int nidx = min(base + 64 + lane, KSELP - 1);
          ull dwn = dg[nidx];
          ull ndwn = ng[nidx];
          ull cur = mailbox[k] | bridge;
          bridge = 0ULL;
          const int lim = V - base;
          ull validm = (lim >= 64) ? ~0ULL : ((~0ULL) >> (64 - lim));
          ull avail = (~cur) & validm;
          const int st = nkeep;
          if (lane == 0) s_start[k] = st;
          while (avail != 0ULL && nkeep < TOPK) {
            int r = __builtin_ctzll(avail);
            if (lane == 0) pickbuf[nkeep] = base + r;
            nkeep++;
            ull dr = readlane64(dw, r);       // critical chain
            bridge |= readlane64(ndw, r);     // off-chain
            avail &= ~(dr | (1ULL << r));
          }
          if (lane == 0) s_np[k] = nkeep - st;
          if (nkeep >= TOPK || base + 64 >= V) {
            if (lane == 0) { s_done = 1; s_n = (nkeep < TOPK) ? nkeep : TOPK; }
            adone = true;
          }
          dw = dwn;
          ndw = ndwn;
        }
      } else if (k >= 1) {
        const int np = s_np[k - 1];
        const int st = s_start[k - 1];
        for (int g = 0; g < np; g += 16) {
          ulonglong2 v[16];
#pragma unroll
          for (int q = 0; q < 16; ++q) {
            int t = min(g + q, np - 1);       // clamped duplicates: idempotent OR
            int row = pickbuf[st + t];
            v[q] = *(const ulonglong2*)(mb + (size_t)row * MW + 2 * lc);
          }
#pragma unroll
          for (int q = 0; q < 16; ++q) { rlo |= v[q].x; rhi |= v[q].y; }
        }
        const int w = k + 1;
        if (w < NCHUNK) {
          ull t = (w & 1) ? rhi : rlo;
          ull word = readlane64(t, w >> 1);
          if (lane == 0) mailbox[w] = word;
        }
      }
    }
  }

  __syncthreads();
  const int n = s_n;
  float* ob = out + (size_t)img * (2 * TOPK * 5) + TOPK * 5;  // class-1 slab
  for (int j = tid; j < n; j += 128) {
    int i = pickbuf[j];
    float4 b = sboxes[(size_t)img * KSEL + i];
    float sc = sscores[(size_t)img * KSEL + i];
    float* o = ob + (size_t)j * 5;
    o[0] = sc; o[1] = b.x; o[2] = b.y; o[3] = b.z; o[4] = b.w;
  }
}

extern "C" void kernel_launch(void* const* d_in, const int* in_sizes, int n_in,
                              void* d_out, int out_size, void* d_ws, size_t ws_size,
                              hipStream_t stream) {
  const float* loc = (const float*)d_in[0];    // [16, 131072, 4]
  const float* conf = (const float*)d_in[1];   // [16*131072, 2]
  const float* prior = (const float*)d_in[2];  // [131072, 4]
  float* out = (float*)d_out;                  // [16, 2, 750, 5]

  char* ws = (char*)d_ws;
  ull* pairs = (ull*)(ws + WS_PAIRS);
  ull* ndiag = (ull*)(ws + WS_NDIAG);          // aliases pairs (dead after rank_decode)
  int* meta = (int*)(ws + WS_MCNT);
  float4* sboxes = (float4*)(ws + WS_BOXES);
  float* sscores = (float*)(ws + WS_SCORES);
  ull* mask = (ull*)(ws + WS_MASK);
  ull* diag = (ull*)(ws + WS_DIAG);
  unsigned int* hist = (unsigned int*)(ws + WS_HIST);
  unsigned int* cnt = (unsigned int*)(ws + WS_CNT);
  unsigned int* pos = (unsigned int*)(ws + WS_POS);

  hipMemsetAsync(d_out, 0, (size_t)out_size * sizeof(float), stream);
  hipMemsetAsync(ws + WS_HIST, 0, 2u * 4194304u, stream);  // hist+cnt (pos needs no init)

  {
    dim3 g(64, NIMG);
    hist_kernel<<<g, 256, 0, stream>>>(conf, hist);
  }
  cutoff_kernel<<<NIMG, 1024, 0, stream>>>(hist, pos, meta, sboxes, sscores);
  {
    dim3 g(64, NIMG);
    scatter_kernel<<<g, 256, 0, stream>>>(conf, pos, cnt, meta, pairs);
  }
  {
    dim3 g((SORTN + 255) / 256, NIMG);
    rank_decode_kernel<<<g, 256, 0, stream>>>(pairs, hist, pos, meta, loc, prior, sboxes, sscores);
  }
  {
    dim3 g(20, 40, NIMG);
    mask_build_kernel<<<g, 256, 0, stream>>>(sboxes, mask, diag, ndiag);
  }
  sweep_kernel<<<NIMG, 128, 0, stream>>>(mask, diag, ndiag, sboxes, sscores, meta, out);
}